// Round 2
// baseline (3223.425 us; speedup 1.0000x reference)
//
#include <hip/hip_runtime.h>

// VectorQuantizerEMA  N=32768 K=8192 D=256  fp32
// Outputs (flat, in order): z_q_st[N*D], commitment[1], idx[N],
//                           new_embed[K*D], new_count[K], new_avg[K*D]
//
// Strategy: bit-exact emulation of the numpy float32 reference pipeline:
//   sz  = np.sum(z*z,-1)   -> AVX512 pairwise-sum order (vstep=16, 8 vaccs, tree)
//   zw  = z @ W.T          -> OpenBLAS sgemm = sequential ascending-k fp32 FMA chain
//   dist= fl(fl(sz - 2*zw) + cw); argmin first-index tie-break.

namespace {
constexpr int kN = 32768;
constexpr int kK = 8192;
constexpr int kD = 256;

// workspace layout (bytes)
constexpr size_t OFF_AVG  = 0;                              // float K*D (zeroed)
constexpr size_t OFF_CNT  = OFF_AVG + (size_t)kK * kD * 4;  // int K (zeroed)
constexpr size_t OFF_COM  = OFF_CNT + (size_t)kK * 4;       // double (zeroed)
constexpr size_t OFF_NS   = OFF_COM + 8;                    // double (zeroed)
constexpr size_t ZERO_BYTES = OFF_NS + 8;                   // 8421392
constexpr size_t OFF_SZ   = 8421440;                        // float N  (||z||^2 fp32-emulated)
constexpr size_t OFF_CW   = OFF_SZ + (size_t)kN * 4;        // float K  (||w||^2 fp32-emulated)
constexpr size_t OFF_WT   = OFF_CW + (size_t)kK * 4;        // float D*K (w transposed)
constexpr size_t OFF_IDX  = OFF_WT + (size_t)kK * kD * 4;   // int N
} // namespace

// ---------------- numpy AVX512 pairwise sum of squares, 128-elem block ------
__device__ __forceinline__ float pw_block128_sq(const float* __restrict__ p) {
#pragma clang fp contract(off)
  float u[16];
#pragma unroll
  for (int l = 0; l < 16; ++l) {
    const float x0 = p[l] * p[l];
    const float x1 = p[16 + l] * p[16 + l];
    const float x2 = p[32 + l] * p[32 + l];
    const float x3 = p[48 + l] * p[48 + l];
    const float x4 = p[64 + l] * p[64 + l];
    const float x5 = p[80 + l] * p[80 + l];
    const float x6 = p[96 + l] * p[96 + l];
    const float x7 = p[112 + l] * p[112 + l];
    u[l] = ((x0 + x1) + (x2 + x3)) + ((x4 + x5) + (x6 + x7));
  }
  float t1[8], t2[4], t3[2];
#pragma unroll
  for (int l = 0; l < 8; ++l) t1[l] = u[l] + u[l + 8];
#pragma unroll
  for (int l = 0; l < 4; ++l) t2[l] = t1[l] + t1[l + 4];
#pragma unroll
  for (int l = 0; l < 2; ++l) t3[l] = t2[l] + t2[l + 2];
  return t3[0] + t3[1];
}

// per-row sum of squares, numpy pairwise order (n=256 -> 128+128 split)
__global__ __launch_bounds__(256) void rowsum_sq(const float* __restrict__ x,
                                                 float* __restrict__ out) {
#pragma clang fp contract(off)
  const int r = blockIdx.x * 256 + threadIdx.x;
  const float* p = x + (size_t)r * kD;
  const float b0 = pw_block128_sq(p);
  const float b1 = pw_block128_sq(p + 128);
  out[r] = b0 + b1;
}

// ---------------- transpose embedding [K][D] -> wT [D][K] ----------------
__global__ __launch_bounds__(256) void transpose_w(const float* __restrict__ w,
                                                   float* __restrict__ wT) {
  __shared__ float tile[64][65];
  const int k0 = blockIdx.x * 64;
  const int d0 = blockIdx.y * 64;
  const int t = threadIdx.x;
#pragma unroll
  for (int p = 0; p < 4; ++p) {
    const int f4 = p * 256 + t;
    const int r  = f4 >> 4;
    const int cq = f4 & 15;
    float4 v = *(const float4*)&w[(size_t)(k0 + r) * kD + d0 + cq * 4];
    tile[r][cq * 4 + 0] = v.x;
    tile[r][cq * 4 + 1] = v.y;
    tile[r][cq * 4 + 2] = v.z;
    tile[r][cq * 4 + 3] = v.w;
  }
  __syncthreads();
#pragma unroll
  for (int p = 0; p < 4; ++p) {
    const int f4 = p * 256 + t;
    const int dr = f4 >> 4;
    const int kq = f4 & 15;
    float4 v = make_float4(tile[kq * 4 + 0][dr], tile[kq * 4 + 1][dr],
                           tile[kq * 4 + 2][dr], tile[kq * 4 + 3][dr]);
    *(float4*)&wT[(size_t)(d0 + dr) * kK + k0 + kq * 4] = v;
  }
}

// ---------------- fp32 argmin, exact sgemm-chain emulation ----------------
// dist_k = fl( fl(sz_n - 2*chain_fma(z_n . w_k)) + cw_k ), first-index argmin.
__global__ __launch_bounds__(256, 2) void argmin_kernel(
    const float* __restrict__ z, const float* __restrict__ wT,
    const float* __restrict__ sz, const float* __restrict__ cw,
    int* __restrict__ idxg, float* __restrict__ out_idx) {
#pragma clang fp contract(off)
  __shared__ float zs[kD * 64];  // [d][row], 64 KiB
  const int tid = threadIdx.x;
  const int tx = tid & 15;
  const int ty = tid >> 4;
  const int r0 = blockIdx.x * 64;

  // stage z tile transposed into LDS
  {
    const int rloc = tid >> 2;
    const int c4 = tid & 3;
    const float* zrow = z + (size_t)(r0 + rloc) * kD;
#pragma unroll
    for (int it = 0; it < 16; ++it) {
      const int dq = c4 * 16 + it;
      float4 v = *(const float4*)&zrow[dq * 4];
      zs[(dq * 4 + 0) * 64 + rloc] = v.x;
      zs[(dq * 4 + 1) * 64 + rloc] = v.y;
      zs[(dq * 4 + 2) * 64 + rloc] = v.z;
      zs[(dq * 4 + 3) * 64 + rloc] = v.w;
    }
  }
  __syncthreads();

  float srow[4];
#pragma unroll
  for (int i = 0; i < 4; ++i) srow[i] = sz[r0 + ty * 4 + i];

  float best[4] = {3.4e38f, 3.4e38f, 3.4e38f, 3.4e38f};
  int bk[4] = {0, 0, 0, 0};

  for (int kt = 0; kt < kK / 64; ++kt) {
    const int k0 = kt * 64;
    float acc[4][4] = {};
#pragma unroll 8
    for (int d = 0; d < kD; ++d) {
      const float4 wv = *(const float4*)&wT[(size_t)d * kK + k0 + tx * 4];
      const float4 zv = *(const float4*)&zs[d * 64 + ty * 4];
      // exact fp32 FMA chain, d ascending — matches OpenBLAS sgemm accumulation
      acc[0][0] = __builtin_fmaf(zv.x, wv.x, acc[0][0]);
      acc[0][1] = __builtin_fmaf(zv.x, wv.y, acc[0][1]);
      acc[0][2] = __builtin_fmaf(zv.x, wv.z, acc[0][2]);
      acc[0][3] = __builtin_fmaf(zv.x, wv.w, acc[0][3]);
      acc[1][0] = __builtin_fmaf(zv.y, wv.x, acc[1][0]);
      acc[1][1] = __builtin_fmaf(zv.y, wv.y, acc[1][1]);
      acc[1][2] = __builtin_fmaf(zv.y, wv.z, acc[1][2]);
      acc[1][3] = __builtin_fmaf(zv.y, wv.w, acc[1][3]);
      acc[2][0] = __builtin_fmaf(zv.z, wv.x, acc[2][0]);
      acc[2][1] = __builtin_fmaf(zv.z, wv.y, acc[2][1]);
      acc[2][2] = __builtin_fmaf(zv.z, wv.z, acc[2][2]);
      acc[2][3] = __builtin_fmaf(zv.z, wv.w, acc[2][3]);
      acc[3][0] = __builtin_fmaf(zv.w, wv.x, acc[3][0]);
      acc[3][1] = __builtin_fmaf(zv.w, wv.y, acc[3][1]);
      acc[3][2] = __builtin_fmaf(zv.w, wv.z, acc[3][2]);
      acc[3][3] = __builtin_fmaf(zv.w, wv.w, acc[3][3]);
    }
    const float4 cwv = *(const float4*)&cw[k0 + tx * 4];
    const float cwa[4] = {cwv.x, cwv.y, cwv.z, cwv.w};
#pragma unroll
    for (int j = 0; j < 4; ++j) {
      const int kk = k0 + tx * 4 + j;
#pragma unroll
      for (int i = 0; i < 4; ++i) {
        const float u = srow[i] - 2.0f * acc[i][j];  // 2*acc exact; single round
        const float dist = u + cwa[j];               // second round
        if (dist < best[i]) {  // strict <: earliest k kept (k ascends per thread)
          best[i] = dist;
          bk[i] = kk;
        }
      }
    }
  }

  // reduce 16 tx candidates per row (consecutive 16-lane groups)
#pragma unroll
  for (int i = 0; i < 4; ++i) {
    float b = best[i];
    int k = bk[i];
#pragma unroll
    for (int m = 1; m < 16; m <<= 1) {
      const float ob = __shfl_xor(b, m);
      const int ok = __shfl_xor(k, m);
      if (ob < b || (ob == b && ok < k)) {  // lowest index on tie
        b = ob;
        k = ok;
      }
    }
    if (tx == 0) {
      const int r = r0 + ty * 4 + i;
      idxg[r] = k;
      out_idx[r] = (float)k;
    }
  }
}

// ---------------- per-row epilogue: z_q_st, commitment partial, scatter ----
__global__ __launch_bounds__(256) void epilogue_row(
    const float* __restrict__ z, const float* __restrict__ emb,
    const int* __restrict__ idxg, float* __restrict__ out_zq,
    float* __restrict__ avgacc, int* __restrict__ cnt,
    double* __restrict__ commit) {
#pragma clang fp contract(off)
  const int n = blockIdx.x;
  const int d = threadIdx.x;
  const int k = idxg[n];
  const float zv = z[(size_t)n * kD + d];
  const float q = emb[(size_t)k * kD + d];
  out_zq[(size_t)n * kD + d] = zv + (q - zv);  // fp32 straight-through like ref
  const float diff = zv - q;
  double v = (double)diff * (double)diff;
#pragma unroll
  for (int m = 32; m; m >>= 1) v += __shfl_xor(v, m);
  __shared__ double part[4];
  const int wv = d >> 6, lane = d & 63;
  if (lane == 0) part[wv] = v;
  atomicAdd(&avgacc[(size_t)k * kD + d], zv);
  __syncthreads();
  if (d == 0) {
    atomicAdd(commit, part[0] + part[1] + part[2] + part[3]);
    atomicAdd(&cnt[k], 1);
  }
}

// ---------------- new_count + n = sum(new_count) ----------------
__global__ __launch_bounds__(256) void newcount_k(const int* __restrict__ cnt,
                                                  const float* __restrict__ ec,
                                                  float* __restrict__ out_cnt,
                                                  double* __restrict__ nsum) {
#pragma clang fp contract(off)
  const int k = blockIdx.x * 256 + threadIdx.x;
  const float nc = 0.99f * ec[k] + 0.01f * (float)cnt[k];
  out_cnt[k] = nc;
  double v = (double)nc;
#pragma unroll
  for (int m = 32; m; m >>= 1) v += __shfl_xor(v, m);
  __shared__ double part[4];
  const int wv = threadIdx.x >> 6, lane = threadIdx.x & 63;
  if (lane == 0) part[wv] = v;
  __syncthreads();
  if (threadIdx.x == 0) atomicAdd(nsum, part[0] + part[1] + part[2] + part[3]);
}

// ---------------- new_avg + new_embed ----------------
__global__ __launch_bounds__(256) void newavg_k(
    const float* __restrict__ avgacc, const float* __restrict__ ea,
    const float* __restrict__ out_cnt, const double* __restrict__ nsum,
    float* __restrict__ out_emb, float* __restrict__ out_avg) {
#pragma clang fp contract(off)
  const int k = blockIdx.x;
  const int d = threadIdx.x;
  const size_t o = (size_t)k * kD + d;
  const float na = 0.99f * ea[o] + 0.01f * avgacc[o];
  out_avg[o] = na;
  const float nf = (float)(*nsum);
  const float nc = out_cnt[k];
  const float keps = 0.08192f;  // fl(K * EPS)
  const float cs = (nc + 1e-5f) / (nf + keps) * nf;
  out_emb[o] = na / cs;
}

// ---------------- commitment finalize ----------------
__global__ void fin_k(const double* __restrict__ commit,
                      float* __restrict__ out_com) {
  out_com[0] = (float)(0.25 * (*commit) / (double)((size_t)kN * kD));
}

extern "C" void kernel_launch(void* const* d_in, const int* in_sizes, int n_in,
                              void* d_out, int out_size, void* d_ws, size_t ws_size,
                              hipStream_t stream) {
  const float* z_e       = (const float*)d_in[0];  // [N,D]
  const float* embedding = (const float*)d_in[1];  // [K,D]
  const float* ema_count = (const float*)d_in[2];  // [K]
  const float* ema_avg   = (const float*)d_in[3];  // [K,D]

  char* ws = (char*)d_ws;
  float*  avg    = (float*)(ws + OFF_AVG);
  int*    cnt    = (int*)(ws + OFF_CNT);
  double* commit = (double*)(ws + OFF_COM);
  double* nsum   = (double*)(ws + OFF_NS);
  float*  sz     = (float*)(ws + OFF_SZ);
  float*  cw     = (float*)(ws + OFF_CW);
  float*  wT     = (float*)(ws + OFF_WT);
  int*    idxg   = (int*)(ws + OFF_IDX);

  float* out_zq  = (float*)d_out;                  // N*D
  float* out_com = out_zq + (size_t)kN * kD;       // 1
  float* out_idx = out_com + 1;                    // N
  float* out_emb = out_idx + kN;                   // K*D
  float* out_cnt = out_emb + (size_t)kK * kD;      // K
  float* out_avg = out_cnt + kK;                   // K*D

  hipMemsetAsync(d_ws, 0, ZERO_BYTES, stream);

  transpose_w<<<dim3(kK / 64, kD / 64), 256, 0, stream>>>(embedding, wT);
  rowsum_sq<<<kN / 256, 256, 0, stream>>>(z_e, sz);
  rowsum_sq<<<kK / 256, 256, 0, stream>>>(embedding, cw);
  argmin_kernel<<<kN / 64, 256, 0, stream>>>(z_e, wT, sz, cw, idxg, out_idx);
  epilogue_row<<<kN, 256, 0, stream>>>(z_e, embedding, idxg, out_zq, avg, cnt,
                                       commit);
  newcount_k<<<kK / 256, 256, 0, stream>>>(cnt, ema_count, out_cnt, nsum);
  newavg_k<<<kK, 256, 0, stream>>>(avg, ema_avg, out_cnt, nsum, out_emb,
                                   out_avg);
  fin_k<<<1, 1, 0, stream>>>(commit, out_com);
}

// Round 3
// 1312.472 us; speedup vs baseline: 2.4560x; 2.4560x over previous
//
#include <hip/hip_runtime.h>

// VectorQuantizerEMA  N=32768 K=8192 D=256  fp32
// Outputs: z_q_st[N*D], commitment[1], idx[N], new_embed[K*D], new_count[K], new_avg[K*D]
//
// Pass 1: bf16-split MFMA GEMM (Keff=768: zh*wh + zl*wh + zh*wl) -> approx score
//         = cw - 2*zw, per-row running min + windowed candidate collection.
// Pass 2: exact fp32-chain recompute of candidates only (bit-exact vs numpy/OpenBLAS),
//         first-index tie-break.

typedef __attribute__((ext_vector_type(8))) short short8;
typedef __attribute__((ext_vector_type(4))) float floatx4;

namespace {
constexpr int kN = 32768;
constexpr int kK = 8192;
constexpr int kD = 256;
constexpr int CAP = 32;
constexpr float WWIN = 1.0e-4f;  // 2*(2*halfulp(512)+chain) + 2*approx_err + slack

// ---- workspace layout (bytes) ----
// zeroed region:
constexpr size_t OFF_AVG  = 0;                               // float K*D
constexpr size_t OFF_CNT  = OFF_AVG + (size_t)kK * kD * 4;   // int K
constexpr size_t OFF_COM  = OFF_CNT + (size_t)kK * 4;        // double
constexpr size_t OFF_NS   = OFF_COM + 8;                     // double
constexpr size_t OFF_GCNT = OFF_NS + 8;                      // uint N
constexpr size_t ZERO_BYTES = OFF_GCNT + (size_t)kN * 4;
// non-zeroed scratch:
constexpr size_t OFF_SZ   = (ZERO_BYTES + 63) & ~(size_t)63; // float N
constexpr size_t OFF_CW   = OFF_SZ + (size_t)kN * 4;         // float K
constexpr size_t OFF_RMIN = OFF_CW + (size_t)kK * 4;         // float N
constexpr size_t OFF_ZH   = OFF_RMIN + (size_t)kN * 4;       // u16 N*D
constexpr size_t OFF_ZL   = OFF_ZH + (size_t)kN * kD * 2;    // u16 N*D
constexpr size_t OFF_WH   = OFF_ZL + (size_t)kN * kD * 2;    // u16 K*D
constexpr size_t OFF_WL   = OFF_WH + (size_t)kK * kD * 2;    // u16 K*D
constexpr size_t OFF_CAND = OFF_WL + (size_t)kK * kD * 2;    // int2 N*CAP
constexpr size_t OFF_IDX  = OFF_CAND + (size_t)kN * CAP * 8; // int N
} // namespace

__device__ __forceinline__ unsigned fmap(float f) {
  unsigned u = __float_as_uint(f);
  return (u & 0x80000000u) ? ~u : (u | 0x80000000u);
}
__device__ __forceinline__ float funmap(unsigned m) {
  unsigned u = (m & 0x80000000u) ? (m & 0x7fffffffu) : ~m;
  return __uint_as_float(u);
}
__device__ __forceinline__ unsigned short f2bf(float f) {
  unsigned u = __float_as_uint(f);
  return (unsigned short)((u + 0x7fffu + ((u >> 16) & 1u)) >> 16);
}
__device__ __forceinline__ float bf2f(unsigned short h) {
  return __uint_as_float(((unsigned)h) << 16);
}
__device__ __forceinline__ void gload16(const void* g, void* l) {
  __builtin_amdgcn_global_load_lds(
      (const __attribute__((address_space(1))) unsigned int*)g,
      (__attribute__((address_space(3))) unsigned int*)l, 16, 0, 0);
}

// ---------------- numpy AVX512 pairwise sum of squares ----------------
__device__ __forceinline__ float pw_block128_sq(const float* __restrict__ p) {
#pragma clang fp contract(off)
  float u[16];
#pragma unroll
  for (int l = 0; l < 16; ++l) {
    const float x0 = p[l] * p[l];
    const float x1 = p[16 + l] * p[16 + l];
    const float x2 = p[32 + l] * p[32 + l];
    const float x3 = p[48 + l] * p[48 + l];
    const float x4 = p[64 + l] * p[64 + l];
    const float x5 = p[80 + l] * p[80 + l];
    const float x6 = p[96 + l] * p[96 + l];
    const float x7 = p[112 + l] * p[112 + l];
    u[l] = ((x0 + x1) + (x2 + x3)) + ((x4 + x5) + (x6 + x7));
  }
  float t1[8], t2[4], t3[2];
#pragma unroll
  for (int l = 0; l < 8; ++l) t1[l] = u[l] + u[l + 8];
#pragma unroll
  for (int l = 0; l < 4; ++l) t2[l] = t1[l] + t1[l + 4];
#pragma unroll
  for (int l = 0; l < 2; ++l) t3[l] = t2[l] + t2[l + 2];
  return t3[0] + t3[1];
}

__global__ __launch_bounds__(256) void rowsum_sq(const float* __restrict__ x,
                                                 float* __restrict__ out) {
#pragma clang fp contract(off)
  const int r = blockIdx.x * 256 + threadIdx.x;
  const float* p = x + (size_t)r * kD;
  out[r] = pw_block128_sq(p) + pw_block128_sq(p + 128);
}

// ---------------- bf16 two-term split ----------------
__global__ __launch_bounds__(256) void split_bf16(const float* __restrict__ x,
                                                  unsigned short* __restrict__ hi,
                                                  unsigned short* __restrict__ lo) {
#pragma clang fp contract(off)
  const size_t i = (size_t)blockIdx.x * 256 + threadIdx.x;
  const float4 v = ((const float4*)x)[i];
  ushort4 h, l;
  h.x = f2bf(v.x); l.x = f2bf(v.x - bf2f(h.x));
  h.y = f2bf(v.y); l.y = f2bf(v.y - bf2f(h.y));
  h.z = f2bf(v.z); l.z = f2bf(v.z - bf2f(h.z));
  h.w = f2bf(v.w); l.w = f2bf(v.w - bf2f(h.w));
  ((ushort4*)hi)[i] = h;
  ((ushort4*)lo)[i] = l;
}

// ---------------- MFMA filter pass ----------------
// Block: 64 z-rows x all 8192 codes (32 strips of 256). 4 waves, each 64x64.
__global__ __launch_bounds__(256, 2) void score_kernel(
    const unsigned short* __restrict__ zh, const unsigned short* __restrict__ zl,
    const unsigned short* __restrict__ wh, const unsigned short* __restrict__ wl,
    const float* __restrict__ cw, unsigned* __restrict__ gcnt,
    int2* __restrict__ gcand, float* __restrict__ rowminf) {
  __shared__ unsigned short Ah[64 * 64];    // 8 KB, XOR-swizzled 16B chunks
  __shared__ unsigned short Bh[256 * 64];   // 32 KB
  __shared__ unsigned ldsmin[64];

  const int tid = threadIdx.x;
  const int wid = tid >> 6;
  const int lane = tid & 63;
  const int l16 = lane & 15;
  const int quad = lane >> 4;
  const int m0 = blockIdx.x * 64;

  if (tid < 64) ldsmin[tid] = 0xFFFFFFFFu;

  for (int nb = 0; nb < 32; ++nb) {
    const int n0 = nb * 256;
    floatx4 acc[4][4];
#pragma unroll
    for (int a = 0; a < 4; ++a)
#pragma unroll
      for (int b = 0; b < 4; ++b) acc[a][b] = (floatx4){0.f, 0.f, 0.f, 0.f};

    for (int kt = 0; kt < 12; ++kt) {
      const int t = kt >> 2;                   // term: zh*wh, zl*wh, zh*wl
      const int d0 = (kt & 3) * 64;
      const unsigned short* As = (t == 1) ? zl : zh;
      const unsigned short* Bs = (t == 2) ? wl : wh;
      __syncthreads();  // prior tile reads complete before overwrite
#pragma unroll
      for (int p = 0; p < 2; ++p) {            // A: 64 rows
        const int q = p * 4 + wid;
        const int r = q * 8 + (lane >> 3);
        const int c = (lane & 7) ^ (r & 7);    // source chunk for swizzled slot
        gload16(As + (size_t)(m0 + r) * kD + d0 + c * 8, &Ah[q * 512]);
      }
#pragma unroll
      for (int p = 0; p < 8; ++p) {            // B: 256 rows
        const int q = p * 4 + wid;
        const int r = q * 8 + (lane >> 3);
        const int c = (lane & 7) ^ (r & 7);
        gload16(Bs + (size_t)(n0 + r) * kD + d0 + c * 8, &Bh[q * 512]);
      }
      __syncthreads();  // drain staging
#pragma unroll
      for (int kc = 0; kc < 2; ++kc) {
        short8 af[4], bfr[4];
#pragma unroll
        for (int mt = 0; mt < 4; ++mt) {
          const int row = mt * 16 + l16;
          const int j = (kc * 4 + quad) ^ (row & 7);
          af[mt] = *(const short8*)&Ah[row * 64 + j * 8];
        }
#pragma unroll
        for (int nt = 0; nt < 4; ++nt) {
          const int row = wid * 64 + nt * 16 + l16;
          const int j = (kc * 4 + quad) ^ (row & 7);
          bfr[nt] = *(const short8*)&Bh[row * 64 + j * 8];
        }
#pragma unroll
        for (int mt = 0; mt < 4; ++mt)
#pragma unroll
          for (int nt = 0; nt < 4; ++nt)
            acc[mt][nt] = __builtin_amdgcn_mfma_f32_16x16x32_bf16(
                af[mt], bfr[nt], acc[mt][nt], 0, 0, 0);
      }
    }

    // ---- epilogue: score = cw - 2*zw; running rowmin; windowed inserts ----
    float cwv[4];
#pragma unroll
    for (int nt = 0; nt < 4; ++nt) cwv[nt] = cw[n0 + wid * 64 + nt * 16 + l16];

    float rm[4][4];
#pragma unroll
    for (int mt = 0; mt < 4; ++mt)
#pragma unroll
      for (int r = 0; r < 4; ++r) {
        float mn = 3.4e38f;
#pragma unroll
        for (int nt = 0; nt < 4; ++nt) {
          const float s = fmaf(-2.0f, acc[mt][nt][r], cwv[nt]);
          acc[mt][nt][r] = s;
          mn = fminf(mn, s);
        }
        rm[mt][r] = mn;
      }
#pragma unroll
    for (int off = 1; off < 16; off <<= 1)
#pragma unroll
      for (int mt = 0; mt < 4; ++mt)
#pragma unroll
        for (int r = 0; r < 4; ++r)
          rm[mt][r] = fminf(rm[mt][r], __shfl_xor(rm[mt][r], off));
    if (l16 == 0) {
#pragma unroll
      for (int mt = 0; mt < 4; ++mt)
#pragma unroll
        for (int r = 0; r < 4; ++r)
          atomicMin(&ldsmin[mt * 16 + quad * 4 + r], fmap(rm[mt][r]));
    }
    __syncthreads();
#pragma unroll
    for (int mt = 0; mt < 4; ++mt)
#pragma unroll
      for (int r = 0; r < 4; ++r) {
        const int ml = mt * 16 + quad * 4 + r;
        const float thr = funmap(ldsmin[ml]) + WWIN;
        if (rm[mt][r] <= thr) {  // lane-local quick reject
#pragma unroll
          for (int nt = 0; nt < 4; ++nt) {
            const float s = acc[mt][nt][r];
            if (s <= thr) {
              const int m = m0 + ml;
              const int n = n0 + wid * 64 + nt * 16 + l16;
              const unsigned pos = atomicAdd(&gcnt[m], 1u);
              if (pos < CAP)
                gcand[(size_t)m * CAP + pos] = make_int2(__float_as_int(s), n);
            }
          }
        }
      }
  }
  __syncthreads();
  if (tid < 64) rowminf[m0 + tid] = funmap(ldsmin[tid]);
}

// ---------------- exact fp32-chain refine (one wave per row) ----------------
__global__ __launch_bounds__(256) void refine_kernel(
    const float* __restrict__ z, const float* __restrict__ emb,
    const float* __restrict__ sz, const float* __restrict__ cw,
    const unsigned* __restrict__ gcnt, const int2* __restrict__ gcand,
    const float* __restrict__ rowminf, int* __restrict__ idxg,
    float* __restrict__ out_idx) {
#pragma clang fp contract(off)
  const int wid = threadIdx.x >> 6;
  const int lane = threadIdx.x & 63;
  const int m = blockIdx.x * 4 + wid;
  const unsigned cnt = gcnt[m];
  const float srow = sz[m];
  const float thr = rowminf[m] + WWIN;
  const float* zrow = z + (size_t)m * kD;
  float bestd = 3.4e38f;
  int bestn = 0x7fffffff;
  if (cnt <= (unsigned)CAP) {
    if (lane < (int)cnt) {
      const int2 cd = gcand[(size_t)m * CAP + lane];
      const float sapp = __int_as_float(cd.x);
      const int n = cd.y;
      if (sapp <= thr) {  // prune junk inserted under stale running min
        const float* wrow = emb + (size_t)n * kD;
        float a = 0.f;
        for (int d4 = 0; d4 < kD; d4 += 4) {
          const float4 zv = *(const float4*)&zrow[d4];
          const float4 wv = *(const float4*)&wrow[d4];
          a = __builtin_fmaf(zv.x, wv.x, a);
          a = __builtin_fmaf(zv.y, wv.y, a);
          a = __builtin_fmaf(zv.z, wv.z, a);
          a = __builtin_fmaf(zv.w, wv.w, a);
        }
        const float u = srow - 2.0f * a;
        bestd = u + cw[n];
        bestn = n;
      }
    }
  } else {
    // overflow fallback (statistically never): exact scan of all K
    for (int base = 0; base < kK; base += 64) {
      const int n = base + lane;
      const float* wrow = emb + (size_t)n * kD;
      float a = 0.f;
      for (int d4 = 0; d4 < kD; d4 += 4) {
        const float4 zv = *(const float4*)&zrow[d4];
        const float4 wv = *(const float4*)&wrow[d4];
        a = __builtin_fmaf(zv.x, wv.x, a);
        a = __builtin_fmaf(zv.y, wv.y, a);
        a = __builtin_fmaf(zv.z, wv.z, a);
        a = __builtin_fmaf(zv.w, wv.w, a);
      }
      const float u = srow - 2.0f * a;
      const float dd = u + cw[n];
      if (dd < bestd) { bestd = dd; bestn = n; }
    }
  }
#pragma unroll
  for (int off = 1; off < 64; off <<= 1) {
    const float od = __shfl_xor(bestd, off);
    const int on = __shfl_xor(bestn, off);
    if (od < bestd || (od == bestd && on < bestn)) { bestd = od; bestn = on; }
  }
  if (lane == 0) {
    idxg[m] = bestn;
    out_idx[m] = (float)bestn;
  }
}

// ---------------- per-row epilogue: z_q_st, commitment, scatter ----------------
__global__ __launch_bounds__(256) void epilogue_row(
    const float* __restrict__ z, const float* __restrict__ emb,
    const int* __restrict__ idxg, float* __restrict__ out_zq,
    float* __restrict__ avgacc, int* __restrict__ cnt,
    double* __restrict__ commit) {
#pragma clang fp contract(off)
  const int n = blockIdx.x;
  const int d = threadIdx.x;
  const int k = idxg[n];
  const float zv = z[(size_t)n * kD + d];
  const float q = emb[(size_t)k * kD + d];
  out_zq[(size_t)n * kD + d] = zv + (q - zv);
  const float diff = zv - q;
  double v = (double)diff * (double)diff;
#pragma unroll
  for (int m = 32; m; m >>= 1) v += __shfl_xor(v, m);
  __shared__ double part[4];
  const int wv = d >> 6, lane = d & 63;
  if (lane == 0) part[wv] = v;
  atomicAdd(&avgacc[(size_t)k * kD + d], zv);
  __syncthreads();
  if (d == 0) {
    atomicAdd(commit, part[0] + part[1] + part[2] + part[3]);
    atomicAdd(&cnt[k], 1);
  }
}

__global__ __launch_bounds__(256) void newcount_k(const int* __restrict__ cnt,
                                                  const float* __restrict__ ec,
                                                  float* __restrict__ out_cnt,
                                                  double* __restrict__ nsum) {
#pragma clang fp contract(off)
  const int k = blockIdx.x * 256 + threadIdx.x;
  const float nc = 0.99f * ec[k] + 0.01f * (float)cnt[k];
  out_cnt[k] = nc;
  double v = (double)nc;
#pragma unroll
  for (int m = 32; m; m >>= 1) v += __shfl_xor(v, m);
  __shared__ double part[4];
  const int wv = threadIdx.x >> 6, lane = threadIdx.x & 63;
  if (lane == 0) part[wv] = v;
  __syncthreads();
  if (threadIdx.x == 0) atomicAdd(nsum, part[0] + part[1] + part[2] + part[3]);
}

__global__ __launch_bounds__(256) void newavg_k(
    const float* __restrict__ avgacc, const float* __restrict__ ea,
    const float* __restrict__ out_cnt, const double* __restrict__ nsum,
    float* __restrict__ out_emb, float* __restrict__ out_avg) {
#pragma clang fp contract(off)
  const int k = blockIdx.x;
  const int d = threadIdx.x;
  const size_t o = (size_t)k * kD + d;
  const float na = 0.99f * ea[o] + 0.01f * avgacc[o];
  out_avg[o] = na;
  const float nf = (float)(*nsum);
  const float nc = out_cnt[k];
  const float keps = 0.08192f;  // fl(K * EPS)
  const float cs = (nc + 1e-5f) / (nf + keps) * nf;
  out_emb[o] = na / cs;
}

__global__ void fin_k(const double* __restrict__ commit,
                      float* __restrict__ out_com) {
  out_com[0] = (float)(0.25 * (*commit) / (double)((size_t)kN * kD));
}

extern "C" void kernel_launch(void* const* d_in, const int* in_sizes, int n_in,
                              void* d_out, int out_size, void* d_ws, size_t ws_size,
                              hipStream_t stream) {
  const float* z_e       = (const float*)d_in[0];
  const float* embedding = (const float*)d_in[1];
  const float* ema_count = (const float*)d_in[2];
  const float* ema_avg   = (const float*)d_in[3];

  char* ws = (char*)d_ws;
  float*  avg    = (float*)(ws + OFF_AVG);
  int*    cnt    = (int*)(ws + OFF_CNT);
  double* commit = (double*)(ws + OFF_COM);
  double* nsum   = (double*)(ws + OFF_NS);
  unsigned* gcnt = (unsigned*)(ws + OFF_GCNT);
  float*  sz     = (float*)(ws + OFF_SZ);
  float*  cw     = (float*)(ws + OFF_CW);
  float*  rmin   = (float*)(ws + OFF_RMIN);
  unsigned short* zh = (unsigned short*)(ws + OFF_ZH);
  unsigned short* zl = (unsigned short*)(ws + OFF_ZL);
  unsigned short* wh = (unsigned short*)(ws + OFF_WH);
  unsigned short* wl = (unsigned short*)(ws + OFF_WL);
  int2*   gcand  = (int2*)(ws + OFF_CAND);
  int*    idxg   = (int*)(ws + OFF_IDX);

  float* out_zq  = (float*)d_out;
  float* out_com = out_zq + (size_t)kN * kD;
  float* out_idx = out_com + 1;
  float* out_emb = out_idx + kN;
  float* out_cnt = out_emb + (size_t)kK * kD;
  float* out_avg = out_cnt + kK;

  hipMemsetAsync(d_ws, 0, ZERO_BYTES, stream);

  rowsum_sq<<<kN / 256, 256, 0, stream>>>(z_e, sz);
  rowsum_sq<<<kK / 256, 256, 0, stream>>>(embedding, cw);
  split_bf16<<<(kN * kD / 4) / 256, 256, 0, stream>>>(z_e, zh, zl);
  split_bf16<<<(kK * kD / 4) / 256, 256, 0, stream>>>(embedding, wh, wl);
  score_kernel<<<kN / 64, 256, 0, stream>>>(zh, zl, wh, wl, cw, gcnt, gcand,
                                            rmin);
  refine_kernel<<<kN / 4, 256, 0, stream>>>(z_e, embedding, sz, cw, gcnt,
                                            gcand, rmin, idxg, out_idx);
  epilogue_row<<<kN, 256, 0, stream>>>(z_e, embedding, idxg, out_zq, avg, cnt,
                                       commit);
  newcount_k<<<kK / 256, 256, 0, stream>>>(cnt, ema_count, out_cnt, nsum);
  newavg_k<<<kK, 256, 0, stream>>>(avg, ema_avg, out_cnt, nsum, out_emb,
                                   out_avg);
  fin_k<<<1, 1, 0, stream>>>(commit, out_com);
}